// Round 13
// baseline (248.740 us; speedup 1.0000x reference)
//
#include <hip/hip_runtime.h>
#include <hip/hip_bf16.h>
#include <hip/hip_fp16.h>
#include <math.h>

__device__ __forceinline__ float leaky02(float x) { return x > 0.f ? x : 0.2f * x; }

// K_prep: fat kernel. Blocks [0,NB1): node1 transform (one wave per node,
// lane owns channels [4*lane..4*lane+3]). Blocks [NB1,...): edge dst count.
__global__ void k_prep(const float* __restrict__ x, const float* __restrict__ W1,
                       const float* __restrict__ att_s, const float* __restrict__ att_d,
                       __half* __restrict__ h1h, float* __restrict__ as1,
                       float* __restrict__ ad1,
                       const int* __restrict__ ei, int* __restrict__ counts,
                       int N, int E, int NB1) {
    int b = blockIdx.x;
    if (b < NB1) {
        int wid = threadIdx.x >> 6;
        int n = b * 4 + wid;
        if (n >= N) return;
        int lane = threadIdx.x & 63;
        int c = lane * 4;
        float x0 = x[n * 3 + 0], x1 = x[n * 3 + 1], x2 = x[n * 3 + 2];
        float4 w0 = *reinterpret_cast<const float4*>(&W1[c]);
        float4 w1 = *reinterpret_cast<const float4*>(&W1[256 + c]);
        float4 w2 = *reinterpret_cast<const float4*>(&W1[512 + c]);
        float h0 = x0 * w0.x + x1 * w1.x + x2 * w2.x;
        float h1_ = x0 * w0.y + x1 * w1.y + x2 * w2.y;
        float h2_ = x0 * w0.z + x1 * w1.z + x2 * w2.z;
        float h3 = x0 * w0.w + x1 * w1.w + x2 * w2.w;
        union { __half2 h[2]; uint2 u; } pk;
        pk.h[0] = __floats2half2_rn(h0, h1_);
        pk.h[1] = __floats2half2_rn(h2_, h3);
        *reinterpret_cast<uint2*>(h1h + (size_t)n * 256 + c) = pk.u;
        float4 as = *reinterpret_cast<const float4*>(&att_s[c]);
        float4 ad = *reinterpret_cast<const float4*>(&att_d[c]);
        float vs = h0 * as.x + h1_ * as.y + h2_ * as.z + h3 * as.w;
        float vd = h0 * ad.x + h1_ * ad.y + h2_ * ad.z + h3 * ad.w;
        #pragma unroll
        for (int m = 1; m < 8; m <<= 1) {
            vs += __shfl_xor(vs, m);
            vd += __shfl_xor(vd, m);
        }
        if ((lane & 7) == 0) {
            as1[n * 8 + (lane >> 3)] = vs;
            ad1[n * 8 + (lane >> 3)] = vd;
        }
    } else {
        int t = (b - NB1) * blockDim.x + threadIdx.x;
        if (t < E) atomicAdd(&counts[ei[E + t]], 1);  // dst row
    }
}

// K_offs2: per-block offsets + cursor; block computes its own prefix.
__global__ void k_offs2(const int* __restrict__ counts,
                        int* __restrict__ offs, int* __restrict__ cursor, int N) {
    __shared__ int red[4];
    __shared__ int wsum[4];
    int b = blockIdx.x;
    int t = threadIdx.x;
    int lane = t & 63, wid = t >> 6;
    int lim = b << 10;
    int s = 0;
    for (int i = t * 4; i < lim; i += 1024) {
        int4 v = *reinterpret_cast<const int4*>(&counts[i]);
        s += v.x + v.y + v.z + v.w + 4;
    }
    #pragma unroll
    for (int m = 1; m < 64; m <<= 1) s += __shfl_xor(s, m);
    if (lane == 0) red[wid] = s;
    __syncthreads();
    int P = red[0] + red[1] + red[2] + red[3];
    int i0 = (b << 10) + t * 4;
    int c0 = 0, c1 = 0, c2 = 0, c3 = 0;
    if (i0 + 3 < N) {
        int4 cv = *reinterpret_cast<const int4*>(&counts[i0]);
        c0 = cv.x + 1; c1 = cv.y + 1; c2 = cv.z + 1; c3 = cv.w + 1;
    } else {
        if (i0 + 0 < N) c0 = counts[i0 + 0] + 1;
        if (i0 + 1 < N) c1 = counts[i0 + 1] + 1;
        if (i0 + 2 < N) c2 = counts[i0 + 2] + 1;
        if (i0 + 3 < N) c3 = counts[i0 + 3] + 1;
    }
    int tsum = c0 + c1 + c2 + c3;
    int incl = tsum;
    #pragma unroll
    for (int off = 1; off < 64; off <<= 1) {
        int tv = __shfl_up(incl, off);
        if (lane >= off) incl += tv;
    }
    if (lane == 63) wsum[wid] = incl;
    __syncthreads();
    int woff = 0;
    for (int w = 0; w < wid; ++w) woff += wsum[w];
    int base = P + woff + incl - tsum;
    int p0 = base;
    int p1 = p0 + c0;
    int p2 = p1 + c1;
    int p3 = p2 + c2;
    int p4 = p3 + c3;
    if (i0 + 0 < N) { cursor[i0 + 0] = p0; offs[i0 + 1] = p1; }
    if (i0 + 1 < N) { cursor[i0 + 1] = p1; offs[i0 + 2] = p2; }
    if (i0 + 2 < N) { cursor[i0 + 2] = p2; offs[i0 + 3] = p3; }
    if (i0 + 3 < N) { cursor[i0 + 3] = p3; offs[i0 + 4] = p4; }
    if (b == 0 && t == 0) offs[0] = 0;
}

__global__ void k_scatter(const int* __restrict__ ei, int* cursor, int* srcs, int E, int N) {
    int t = blockIdx.x * blockDim.x + threadIdx.x;
    if (t < E) {
        int s = ei[t], d = ei[E + t];
        int pos = atomicAdd(&cursor[d], 1);
        srcs[pos] = s;
    } else if (t < E + N) {
        int i = t - E;
        int pos = atomicAdd(&cursor[i], 1);
        srcs[pos] = i;  // self loop
    }
}

// K_agg1n2: agg1 (28-VGPR main loop) + node2 tail via LDS.
// feat stored with a ROTATION swizzle (zero pad): channel u of q-group at
// word q*64 + ((u + 8q) & 63). Read banks for the 4 q-groups become
// {u, u+8, u+16, u+24} mod 32 -> conflict-free at b32 AND b128 granularity.
// Total LDS stays exactly 20480 B -> 8 blocks/CU (R11 lesson: 20992 B cost
// a block and 7% occupancy). W2 LDS 2-way read is free (m136).
__global__ void k_agg1n2(const __half* __restrict__ h1h, const float* __restrict__ as1,
                         const float* __restrict__ ad1, const float* __restrict__ b1,
                         const float* __restrict__ W2, const float* __restrict__ att_s2,
                         const float* __restrict__ att_d2,
                         const int* __restrict__ offs, const int* __restrict__ srcs,
                         __half* __restrict__ h2h, float* __restrict__ as2,
                         float* __restrict__ ad2, int N) {
    __shared__ float w_lds[4096];
    __shared__ float feat_lds[1024];   // 4 waves x 256, rotation-swizzled
    int t = threadIdx.x;
    {   // thread t stages W2 row k=t into the swizzled slot
        int k = t;
        const float4* src = reinterpret_cast<const float4*>(&W2[k * 16]);
        int base = ((k >> 7) << 11) + ((k & 63) << 5) + (((k >> 6) & 1) << 4);
        float4 v0 = src[0], v1 = src[1], v2 = src[2], v3 = src[3];
        *reinterpret_cast<float4*>(&w_lds[base + 0]) = v0;
        *reinterpret_cast<float4*>(&w_lds[base + 4]) = v1;
        *reinterpret_cast<float4*>(&w_lds[base + 8]) = v2;
        *reinterpret_cast<float4*>(&w_lds[base + 12]) = v3;
    }
    __syncthreads();

    int wid = t >> 6;
    int d = blockIdx.x * 4 + wid;
    if (d >= N) return;
    int lane = t & 63;
    int head = lane >> 3;
    int po = lane >> 3;
    int ph = lane & 7;
    float ad_p = ad1[d * 8 + ph];
    int beg = offs[d], end = offs[d + 1];
    float denom = 0.f, a0 = 0.f, a1 = 0.f, a2 = 0.f, a3 = 0.f;
    for (int cb = beg; cb < end; cb += 64) {
        int idx = cb + lane;
        int myS = srcs[idx < end ? idx : end - 1];
        int cnt = min(64, end - cb);   // wave-uniform
        float p8[8];
        #pragma unroll
        for (int j = 0; j < 8; ++j) {
            int s = __shfl(myS, po * 8 + j);
            p8[j] = __expf(leaky02(as1[s * 8 + ph] + ad_p));
        }
        for (int kb = 0; kb < cnt; kb += 8) {
            #pragma unroll
            for (int j = 0; j < 8; ++j) {
                int k = kb + j;            // wave-uniform
                if (k < cnt) {             // uniform branch: convergent shfls
                    int s = __shfl(myS, k);
                    float p = __shfl(p8[j], kb + head);
                    denom += p;
                    uint2 raw = *reinterpret_cast<const uint2*>(
                        h1h + (size_t)s * 256 + lane * 4);
                    union { unsigned u; __half2 h; } u0, u1;
                    u0.u = raw.x; u1.u = raw.y;
                    float2 f01 = __half22float2(u0.h);
                    float2 f23 = __half22float2(u1.h);
                    a0 += p * f01.x; a1 += p * f01.y;
                    a2 += p * f23.x; a3 += p * f23.y;
                }
            }
        }
    }
    float inv = 1.f / (denom + 1e-16f);
    int c = lane * 4;
    float4 bv = *reinterpret_cast<const float4*>(&b1[c]);
    float r0 = a0 * inv + bv.x;
    float r1 = a1 * inv + bv.y;
    float r2 = a2 * inv + bv.z;
    float r3 = a3 * inv + bv.w;
    r0 = r0 > 0.f ? r0 : (__expf(r0) - 1.f);
    r1 = r1 > 0.f ? r1 : (__expf(r1) - 1.f);
    r2 = r2 > 0.f ? r2 : (__expf(r2) - 1.f);
    r3 = r3 > 0.f ? r3 : (__expf(r3) - 1.f);
    // ---- node2 tail ----
    // store: lane = 16*qw + ow owns channels u = 4*ow.. of q-group qw;
    // rotated slot (4*ow + 8*qw) & 63 stays float4-aligned, no mid-wrap.
    {
        int qw = lane >> 4, ow = lane & 15;
        float4 fv; fv.x = r0; fv.y = r1; fv.z = r2; fv.w = r3;
        *reinterpret_cast<float4*>(
            &feat_lds[wid * 256 + qw * 64 + ((4 * ow + 8 * qw) & 63)]) = fv;
    }
    int o = lane & 15, q = lane >> 4;
    const float* fl = &feat_lds[wid * 256 + q * 64];
    const float* w = w_lds + ((q >> 1) << 11) + ((q & 1) << 4) + o;  // + u*32
    int rot = 8 * q;
    float acc = 0.f;
    #pragma unroll 8
    for (int u = 0; u < 64; ++u)
        acc += fl[(u + rot) & 63] * w[u * 32];
    acc += __shfl_xor(acc, 16);
    acc += __shfl_xor(acc, 32);    // all lanes hold h2[d][o]
    if (lane < 16) h2h[d * 16 + o] = __float2half(acc);
    float ts = acc * att_s2[o], td = acc * att_d2[o];
    #pragma unroll
    for (int m = 1; m < 16; m <<= 1) {
        ts += __shfl_xor(ts, m);
        td += __shfl_xor(td, m);
    }
    if (lane == 0) { as2[d] = ts; ad2[d] = td; }
}

// K_agg2: one wave per dst. 16 edge-groups x 4 lanes owning 4 channels each.
// All lanes execute every shfl (convergent); accumulate predicated only.
__global__ void k_agg2(const __half* __restrict__ h2h, const float* __restrict__ as2,
                       const float* __restrict__ ad2, const float* __restrict__ b2,
                       const int* __restrict__ offs, const int* __restrict__ srcs,
                       float* __restrict__ out, int N) {
    int wid = threadIdx.x >> 6;
    int d = blockIdx.x * 4 + wid;
    if (d >= N) return;
    int lane = threadIdx.x & 63;
    int cl = lane & 3, eg = lane >> 2;
    float ad = ad2[d];
    int beg = offs[d], end = offs[d + 1];
    float denom = 0.f, a0 = 0.f, a1 = 0.f, a2 = 0.f, a3 = 0.f;
    for (int cb = beg; cb < end; cb += 64) {
        int idx = cb + lane;
        int myS = srcs[idx < end ? idx : end - 1];
        #pragma unroll
        for (int cc = 0; cc < 4; ++cc) {
            int s = __shfl(myS, cc * 16 + eg);   // convergent
            int epos = cb + cc * 16 + eg;
            if (epos < end) {
                float e = leaky02(as2[s] + ad);
                float p = __expf(e);
                denom += p;
                uint2 raw = *reinterpret_cast<const uint2*>(h2h + (size_t)s * 16 + cl * 4);
                union { unsigned u; __half2 h; } u0, u1;
                u0.u = raw.x; u1.u = raw.y;
                float2 f01 = __half22float2(u0.h);
                float2 f23 = __half22float2(u1.h);
                a0 += p * f01.x; a1 += p * f01.y; a2 += p * f23.x; a3 += p * f23.y;
            }
        }
    }
    #pragma unroll
    for (int m = 4; m < 64; m <<= 1) {
        denom += __shfl_xor(denom, m);
        a0 += __shfl_xor(a0, m);
        a1 += __shfl_xor(a1, m);
        a2 += __shfl_xor(a2, m);
        a3 += __shfl_xor(a3, m);
    }
    if (eg == 0) {
        float inv = 1.f / (denom + 1e-16f);
        int c = cl * 4;
        float4 r;
        r.x = a0 * inv + b2[c + 0];
        r.y = a1 * inv + b2[c + 1];
        r.z = a2 * inv + b2[c + 2];
        r.w = a3 * inv + b2[c + 3];
        *reinterpret_cast<float4*>(&out[d * 16 + c]) = r;
    }
}

extern "C" void kernel_launch(void* const* d_in, const int* in_sizes, int n_in,
                              void* d_out, int out_size, void* d_ws, size_t ws_size,
                              hipStream_t stream) {
    const float* x       = (const float*)d_in[0];
    const int*   ei      = (const int*)d_in[1];
    const float* W1      = (const float*)d_in[2];
    const float* att_s1  = (const float*)d_in[3];
    const float* att_d1  = (const float*)d_in[4];
    const float* b1      = (const float*)d_in[5];
    const float* W2      = (const float*)d_in[6];
    const float* att_s2  = (const float*)d_in[7];
    const float* att_d2  = (const float*)d_in[8];
    const float* b2      = (const float*)d_in[9];
    float* out = (float*)d_out;

    const int N = in_sizes[0] / 3;
    const int E = in_sizes[1] / 2;
    const int Etot = E + N;
    const int NB = (N + 1023) / 1024;  // scan blocks

    // carve workspace (16B aligned slices)
    char* w = (char*)d_ws;
    auto alloc = [&](size_t bytes) -> void* {
        void* p = (void*)w;
        w += (bytes + 15) & ~(size_t)15;
        return p;
    };
    int* counts   = (int*)alloc((size_t)N * 4);
    int* offs     = (int*)alloc((size_t)(N + 1) * 4);
    int* cursor   = (int*)alloc((size_t)N * 4);
    int* srcs     = (int*)alloc((size_t)Etot * 4);
    __half* h1h   = (__half*)alloc((size_t)N * 256 * 2);
    float* as1    = (float*)alloc((size_t)N * 8 * 4);
    float* ad1    = (float*)alloc((size_t)N * 8 * 4);
    __half* h2h   = (__half*)alloc((size_t)N * 16 * 2);
    float* as2    = (float*)alloc((size_t)N * 4);
    float* ad2    = (float*)alloc((size_t)N * 4);
    (void)ws_size; (void)n_in; (void)out_size;

    const int B = 256;
    const int NB1 = (N + 3) / 4;            // node1 blocks in k_prep
    const int NBc = (E + B - 1) / B;        // count blocks in k_prep

    hipMemsetAsync(counts, 0, (size_t)N * 4, stream);
    hipLaunchKernelGGL(k_prep, dim3(NB1 + NBc), dim3(B), 0, stream,
                       x, W1, att_s1, att_d1, h1h, as1, ad1, ei, counts, N, E, NB1);
    hipLaunchKernelGGL(k_offs2, dim3(NB), dim3(B), 0, stream, counts, offs, cursor, N);
    hipLaunchKernelGGL(k_scatter, dim3((Etot + B - 1) / B), dim3(B), 0, stream,
                       ei, cursor, srcs, E, N);
    hipLaunchKernelGGL(k_agg1n2, dim3((N + 3) / 4), dim3(B), 0, stream,
                       h1h, as1, ad1, b1, W2, att_s2, att_d2, offs, srcs,
                       h2h, as2, ad2, N);
    hipLaunchKernelGGL(k_agg2, dim3((N + 3) / 4), dim3(B), 0, stream,
                       h2h, as2, ad2, b2, offs, srcs, out, N);
}

// Round 14
// 235.690 us; speedup vs baseline: 1.0554x; 1.0554x over previous
//
#include <hip/hip_runtime.h>
#include <hip/hip_bf16.h>
#include <hip/hip_fp16.h>
#include <math.h>

__device__ __forceinline__ float leaky02(float x) { return x > 0.f ? x : 0.2f * x; }

// K_prep: fat kernel. Blocks [0,NB1): node1 transform (one wave per node,
// lane owns channels [4*lane..4*lane+3]). Blocks [NB1,...): edge dst count.
__global__ void k_prep(const float* __restrict__ x, const float* __restrict__ W1,
                       const float* __restrict__ att_s, const float* __restrict__ att_d,
                       __half* __restrict__ h1h, float* __restrict__ as1,
                       float* __restrict__ ad1,
                       const int* __restrict__ ei, int* __restrict__ counts,
                       int N, int E, int NB1) {
    int b = blockIdx.x;
    if (b < NB1) {
        int wid = threadIdx.x >> 6;
        int n = b * 4 + wid;
        if (n >= N) return;
        int lane = threadIdx.x & 63;
        int c = lane * 4;
        float x0 = x[n * 3 + 0], x1 = x[n * 3 + 1], x2 = x[n * 3 + 2];
        float4 w0 = *reinterpret_cast<const float4*>(&W1[c]);
        float4 w1 = *reinterpret_cast<const float4*>(&W1[256 + c]);
        float4 w2 = *reinterpret_cast<const float4*>(&W1[512 + c]);
        float h0 = x0 * w0.x + x1 * w1.x + x2 * w2.x;
        float h1_ = x0 * w0.y + x1 * w1.y + x2 * w2.y;
        float h2_ = x0 * w0.z + x1 * w1.z + x2 * w2.z;
        float h3 = x0 * w0.w + x1 * w1.w + x2 * w2.w;
        union { __half2 h[2]; uint2 u; } pk;
        pk.h[0] = __floats2half2_rn(h0, h1_);
        pk.h[1] = __floats2half2_rn(h2_, h3);
        *reinterpret_cast<uint2*>(h1h + (size_t)n * 256 + c) = pk.u;
        float4 as = *reinterpret_cast<const float4*>(&att_s[c]);
        float4 ad = *reinterpret_cast<const float4*>(&att_d[c]);
        float vs = h0 * as.x + h1_ * as.y + h2_ * as.z + h3 * as.w;
        float vd = h0 * ad.x + h1_ * ad.y + h2_ * ad.z + h3 * ad.w;
        #pragma unroll
        for (int m = 1; m < 8; m <<= 1) {
            vs += __shfl_xor(vs, m);
            vd += __shfl_xor(vd, m);
        }
        if ((lane & 7) == 0) {
            as1[n * 8 + (lane >> 3)] = vs;
            ad1[n * 8 + (lane >> 3)] = vd;
        }
    } else {
        int t = (b - NB1) * blockDim.x + threadIdx.x;
        if (t < E) atomicAdd(&counts[ei[E + t]], 1);  // dst row
    }
}

// K_offs2: per-block offsets + cursor; block computes its own prefix.
__global__ void k_offs2(const int* __restrict__ counts,
                        int* __restrict__ offs, int* __restrict__ cursor, int N) {
    __shared__ int red[4];
    __shared__ int wsum[4];
    int b = blockIdx.x;
    int t = threadIdx.x;
    int lane = t & 63, wid = t >> 6;
    int lim = b << 10;
    int s = 0;
    for (int i = t * 4; i < lim; i += 1024) {
        int4 v = *reinterpret_cast<const int4*>(&counts[i]);
        s += v.x + v.y + v.z + v.w + 4;
    }
    #pragma unroll
    for (int m = 1; m < 64; m <<= 1) s += __shfl_xor(s, m);
    if (lane == 0) red[wid] = s;
    __syncthreads();
    int P = red[0] + red[1] + red[2] + red[3];
    int i0 = (b << 10) + t * 4;
    int c0 = 0, c1 = 0, c2 = 0, c3 = 0;
    if (i0 + 3 < N) {
        int4 cv = *reinterpret_cast<const int4*>(&counts[i0]);
        c0 = cv.x + 1; c1 = cv.y + 1; c2 = cv.z + 1; c3 = cv.w + 1;
    } else {
        if (i0 + 0 < N) c0 = counts[i0 + 0] + 1;
        if (i0 + 1 < N) c1 = counts[i0 + 1] + 1;
        if (i0 + 2 < N) c2 = counts[i0 + 2] + 1;
        if (i0 + 3 < N) c3 = counts[i0 + 3] + 1;
    }
    int tsum = c0 + c1 + c2 + c3;
    int incl = tsum;
    #pragma unroll
    for (int off = 1; off < 64; off <<= 1) {
        int tv = __shfl_up(incl, off);
        if (lane >= off) incl += tv;
    }
    if (lane == 63) wsum[wid] = incl;
    __syncthreads();
    int woff = 0;
    for (int w = 0; w < wid; ++w) woff += wsum[w];
    int base = P + woff + incl - tsum;
    int p0 = base;
    int p1 = p0 + c0;
    int p2 = p1 + c1;
    int p3 = p2 + c2;
    int p4 = p3 + c3;
    if (i0 + 0 < N) { cursor[i0 + 0] = p0; offs[i0 + 1] = p1; }
    if (i0 + 1 < N) { cursor[i0 + 1] = p1; offs[i0 + 2] = p2; }
    if (i0 + 2 < N) { cursor[i0 + 2] = p2; offs[i0 + 3] = p3; }
    if (i0 + 3 < N) { cursor[i0 + 3] = p3; offs[i0 + 4] = p4; }
    if (b == 0 && t == 0) offs[0] = 0;
}

__global__ void k_scatter(const int* __restrict__ ei, int* cursor, int* srcs, int E, int N) {
    int t = blockIdx.x * blockDim.x + threadIdx.x;
    if (t < E) {
        int s = ei[t], d = ei[E + t];
        int pos = atomicAdd(&cursor[d], 1);
        srcs[pos] = s;
    } else if (t < E + N) {
        int i = t - E;
        int pos = atomicAdd(&cursor[i], 1);
        srcs[pos] = i;  // self loop
    }
}

// K_agg1n2: agg1 (28-VGPR main loop) + node2 tail via LDS.
// W2 staging is DST-LINEAR (thread t writes consecutive float4 at
// d = p*1024 + t*4, decoding (k,o) by inverting the swizzle): 64 lanes x
// 4 words = all 32 banks -> conflict-free (R12 diagnosis: the old
// src-ordered staging at word-stride 32 was the stubborn 1.1e7-cycle
// bank conflict, all lanes on banks 0-3).
// feat_lds is the plain linear layout (R10): its residual 4-way broadcast
// read conflict (~3e6 cyc) is cheaper than rotation's VALU cost (R12).
// W2 read layout: banks ((q&1)*16+o) -> 2-way (free, m136).
// LDS total 20480 B = exactly 8 blocks/CU (R11 lesson: don't pad past it).
__global__ void k_agg1n2(const __half* __restrict__ h1h, const float* __restrict__ as1,
                         const float* __restrict__ ad1, const float* __restrict__ b1,
                         const float* __restrict__ W2, const float* __restrict__ att_s2,
                         const float* __restrict__ att_d2,
                         const int* __restrict__ offs, const int* __restrict__ srcs,
                         __half* __restrict__ h2h, float* __restrict__ as2,
                         float* __restrict__ ad2, int N) {
    __shared__ float w_lds[4096];
    __shared__ float feat_lds[1024];   // 4 waves x 256 channels (linear)
    int t = threadIdx.x;
    #pragma unroll
    for (int p = 0; p < 4; ++p) {
        int d = p * 1024 + t * 4;          // linear dst word (float4-aligned)
        int hi = d >> 11;                  // k bit 7
        int r = d & 2047;
        int row = r >> 5;                  // k bits 0..5
        int rem = r & 31;
        int half = rem >> 4;               // k bit 6
        int o = rem & 15;                  // o in {0,4,8,12}
        int k = (hi << 7) | (half << 6) | row;
        *reinterpret_cast<float4*>(&w_lds[d]) =
            *reinterpret_cast<const float4*>(&W2[k * 16 + o]);
    }
    __syncthreads();

    int wid = t >> 6;
    int d = blockIdx.x * 4 + wid;
    if (d >= N) return;
    int lane = t & 63;
    int head = lane >> 3;
    int po = lane >> 3;
    int ph = lane & 7;
    float ad_p = ad1[d * 8 + ph];
    int beg = offs[d], end = offs[d + 1];
    float denom = 0.f, a0 = 0.f, a1 = 0.f, a2 = 0.f, a3 = 0.f;
    for (int cb = beg; cb < end; cb += 64) {
        int idx = cb + lane;
        int myS = srcs[idx < end ? idx : end - 1];
        int cnt = min(64, end - cb);   // wave-uniform
        float p8[8];
        #pragma unroll
        for (int j = 0; j < 8; ++j) {
            int s = __shfl(myS, po * 8 + j);
            p8[j] = __expf(leaky02(as1[s * 8 + ph] + ad_p));
        }
        for (int kb = 0; kb < cnt; kb += 8) {
            #pragma unroll
            for (int j = 0; j < 8; ++j) {
                int k = kb + j;            // wave-uniform
                if (k < cnt) {             // uniform branch: convergent shfls
                    int s = __shfl(myS, k);
                    float p = __shfl(p8[j], kb + head);
                    denom += p;
                    uint2 raw = *reinterpret_cast<const uint2*>(
                        h1h + (size_t)s * 256 + lane * 4);
                    union { unsigned u; __half2 h; } u0, u1;
                    u0.u = raw.x; u1.u = raw.y;
                    float2 f01 = __half22float2(u0.h);
                    float2 f23 = __half22float2(u1.h);
                    a0 += p * f01.x; a1 += p * f01.y;
                    a2 += p * f23.x; a3 += p * f23.y;
                }
            }
        }
    }
    float inv = 1.f / (denom + 1e-16f);
    int c = lane * 4;
    float4 bv = *reinterpret_cast<const float4*>(&b1[c]);
    float r0 = a0 * inv + bv.x;
    float r1 = a1 * inv + bv.y;
    float r2 = a2 * inv + bv.z;
    float r3 = a3 * inv + bv.w;
    r0 = r0 > 0.f ? r0 : (__expf(r0) - 1.f);
    r1 = r1 > 0.f ? r1 : (__expf(r1) - 1.f);
    r2 = r2 > 0.f ? r2 : (__expf(r2) - 1.f);
    r3 = r3 > 0.f ? r3 : (__expf(r3) - 1.f);
    // ---- node2 tail: feat -> LDS (wave-private row; no barrier needed) ----
    float4 fv; fv.x = r0; fv.y = r1; fv.z = r2; fv.w = r3;
    *reinterpret_cast<float4*>(&feat_lds[wid * 256 + c]) = fv;
    int o = lane & 15, q = lane >> 4;
    const float* fl = &feat_lds[wid * 256 + q * 64];
    const float* w = w_lds + ((q >> 1) << 11) + ((q & 1) << 4) + o;  // + j*32
    float acc = 0.f;
    #pragma unroll 8
    for (int j = 0; j < 64; ++j)
        acc += fl[j] * w[j * 32];
    acc += __shfl_xor(acc, 16);
    acc += __shfl_xor(acc, 32);    // all lanes hold h2[d][o]
    if (lane < 16) h2h[d * 16 + o] = __float2half(acc);
    float ts = acc * att_s2[o], td = acc * att_d2[o];
    #pragma unroll
    for (int m = 1; m < 16; m <<= 1) {
        ts += __shfl_xor(ts, m);
        td += __shfl_xor(td, m);
    }
    if (lane == 0) { as2[d] = ts; ad2[d] = td; }
}

// K_agg2: one wave per dst. 16 edge-groups x 4 lanes owning 4 channels each.
// All lanes execute every shfl (convergent); accumulate predicated only.
__global__ void k_agg2(const __half* __restrict__ h2h, const float* __restrict__ as2,
                       const float* __restrict__ ad2, const float* __restrict__ b2,
                       const int* __restrict__ offs, const int* __restrict__ srcs,
                       float* __restrict__ out, int N) {
    int wid = threadIdx.x >> 6;
    int d = blockIdx.x * 4 + wid;
    if (d >= N) return;
    int lane = threadIdx.x & 63;
    int cl = lane & 3, eg = lane >> 2;
    float ad = ad2[d];
    int beg = offs[d], end = offs[d + 1];
    float denom = 0.f, a0 = 0.f, a1 = 0.f, a2 = 0.f, a3 = 0.f;
    for (int cb = beg; cb < end; cb += 64) {
        int idx = cb + lane;
        int myS = srcs[idx < end ? idx : end - 1];
        #pragma unroll
        for (int cc = 0; cc < 4; ++cc) {
            int s = __shfl(myS, cc * 16 + eg);   // convergent
            int epos = cb + cc * 16 + eg;
            if (epos < end) {
                float e = leaky02(as2[s] + ad);
                float p = __expf(e);
                denom += p;
                uint2 raw = *reinterpret_cast<const uint2*>(h2h + (size_t)s * 16 + cl * 4);
                union { unsigned u; __half2 h; } u0, u1;
                u0.u = raw.x; u1.u = raw.y;
                float2 f01 = __half22float2(u0.h);
                float2 f23 = __half22float2(u1.h);
                a0 += p * f01.x; a1 += p * f01.y; a2 += p * f23.x; a3 += p * f23.y;
            }
        }
    }
    #pragma unroll
    for (int m = 4; m < 64; m <<= 1) {
        denom += __shfl_xor(denom, m);
        a0 += __shfl_xor(a0, m);
        a1 += __shfl_xor(a1, m);
        a2 += __shfl_xor(a2, m);
        a3 += __shfl_xor(a3, m);
    }
    if (eg == 0) {
        float inv = 1.f / (denom + 1e-16f);
        int c = cl * 4;
        float4 r;
        r.x = a0 * inv + b2[c + 0];
        r.y = a1 * inv + b2[c + 1];
        r.z = a2 * inv + b2[c + 2];
        r.w = a3 * inv + b2[c + 3];
        *reinterpret_cast<float4*>(&out[d * 16 + c]) = r;
    }
}

extern "C" void kernel_launch(void* const* d_in, const int* in_sizes, int n_in,
                              void* d_out, int out_size, void* d_ws, size_t ws_size,
                              hipStream_t stream) {
    const float* x       = (const float*)d_in[0];
    const int*   ei      = (const int*)d_in[1];
    const float* W1      = (const float*)d_in[2];
    const float* att_s1  = (const float*)d_in[3];
    const float* att_d1  = (const float*)d_in[4];
    const float* b1      = (const float*)d_in[5];
    const float* W2      = (const float*)d_in[6];
    const float* att_s2  = (const float*)d_in[7];
    const float* att_d2  = (const float*)d_in[8];
    const float* b2      = (const float*)d_in[9];
    float* out = (float*)d_out;

    const int N = in_sizes[0] / 3;
    const int E = in_sizes[1] / 2;
    const int Etot = E + N;
    const int NB = (N + 1023) / 1024;  // scan blocks

    // carve workspace (16B aligned slices)
    char* w = (char*)d_ws;
    auto alloc = [&](size_t bytes) -> void* {
        void* p = (void*)w;
        w += (bytes + 15) & ~(size_t)15;
        return p;
    };
    int* counts   = (int*)alloc((size_t)N * 4);
    int* offs     = (int*)alloc((size_t)(N + 1) * 4);
    int* cursor   = (int*)alloc((size_t)N * 4);
    int* srcs     = (int*)alloc((size_t)Etot * 4);
    __half* h1h   = (__half*)alloc((size_t)N * 256 * 2);
    float* as1    = (float*)alloc((size_t)N * 8 * 4);
    float* ad1    = (float*)alloc((size_t)N * 8 * 4);
    __half* h2h   = (__half*)alloc((size_t)N * 16 * 2);
    float* as2    = (float*)alloc((size_t)N * 4);
    float* ad2    = (float*)alloc((size_t)N * 4);
    (void)ws_size; (void)n_in; (void)out_size;

    const int B = 256;
    const int NB1 = (N + 3) / 4;            // node1 blocks in k_prep
    const int NBc = (E + B - 1) / B;        // count blocks in k_prep

    hipMemsetAsync(counts, 0, (size_t)N * 4, stream);
    hipLaunchKernelGGL(k_prep, dim3(NB1 + NBc), dim3(B), 0, stream,
                       x, W1, att_s1, att_d1, h1h, as1, ad1, ei, counts, N, E, NB1);
    hipLaunchKernelGGL(k_offs2, dim3(NB), dim3(B), 0, stream, counts, offs, cursor, N);
    hipLaunchKernelGGL(k_scatter, dim3((Etot + B - 1) / B), dim3(B), 0, stream,
                       ei, cursor, srcs, E, N);
    hipLaunchKernelGGL(k_agg1n2, dim3((N + 3) / 4), dim3(B), 0, stream,
                       h1h, as1, ad1, b1, W2, att_s2, att_d2, offs, srcs,
                       h2h, as2, ad2, N);
    hipLaunchKernelGGL(k_agg2, dim3((N + 3) / 4), dim3(B), 0, stream,
                       h2h, as2, ad2, b2, offs, srcs, out, N);
}

// Round 15
// 224.355 us; speedup vs baseline: 1.1087x; 1.0505x over previous
//
#include <hip/hip_runtime.h>
#include <hip/hip_bf16.h>
#include <hip/hip_fp16.h>
#include <math.h>

__device__ __forceinline__ float leaky02(float x) { return x > 0.f ? x : 0.2f * x; }

// K_prep: fat kernel. Blocks [0,NB1): node1 transform. Blocks [NB1,...):
// edge dst count + per-edge position (epos = old count), coalesced store.
__global__ void k_prep(const float* __restrict__ x, const float* __restrict__ W1,
                       const float* __restrict__ att_s, const float* __restrict__ att_d,
                       __half* __restrict__ h1h, float* __restrict__ as1,
                       float* __restrict__ ad1,
                       const int* __restrict__ ei, int* __restrict__ counts,
                       int* __restrict__ epos,
                       int N, int E, int NB1) {
    int b = blockIdx.x;
    if (b < NB1) {
        int wid = threadIdx.x >> 6;
        int n = b * 4 + wid;
        if (n >= N) return;
        int lane = threadIdx.x & 63;
        int c = lane * 4;
        float x0 = x[n * 3 + 0], x1 = x[n * 3 + 1], x2 = x[n * 3 + 2];
        float4 w0 = *reinterpret_cast<const float4*>(&W1[c]);
        float4 w1 = *reinterpret_cast<const float4*>(&W1[256 + c]);
        float4 w2 = *reinterpret_cast<const float4*>(&W1[512 + c]);
        float h0 = x0 * w0.x + x1 * w1.x + x2 * w2.x;
        float h1_ = x0 * w0.y + x1 * w1.y + x2 * w2.y;
        float h2_ = x0 * w0.z + x1 * w1.z + x2 * w2.z;
        float h3 = x0 * w0.w + x1 * w1.w + x2 * w2.w;
        union { __half2 h[2]; uint2 u; } pk;
        pk.h[0] = __floats2half2_rn(h0, h1_);
        pk.h[1] = __floats2half2_rn(h2_, h3);
        *reinterpret_cast<uint2*>(h1h + (size_t)n * 256 + c) = pk.u;
        float4 as = *reinterpret_cast<const float4*>(&att_s[c]);
        float4 ad = *reinterpret_cast<const float4*>(&att_d[c]);
        float vs = h0 * as.x + h1_ * as.y + h2_ * as.z + h3 * as.w;
        float vd = h0 * ad.x + h1_ * ad.y + h2_ * ad.z + h3 * ad.w;
        #pragma unroll
        for (int m = 1; m < 8; m <<= 1) {
            vs += __shfl_xor(vs, m);
            vd += __shfl_xor(vd, m);
        }
        if ((lane & 7) == 0) {
            as1[n * 8 + (lane >> 3)] = vs;
            ad1[n * 8 + (lane >> 3)] = vd;
        }
    } else {
        int t = (b - NB1) * blockDim.x + threadIdx.x;
        if (t < E) {
            int d = ei[E + t];
            epos[t] = atomicAdd(&counts[d], 1);   // position within dst segment
        }
    }
}

// K_offs2: per-block offsets; block computes its own prefix. Also places the
// self-loop at the LAST slot of each segment (srcs[offs[i+1]-1] = i), so the
// scatter kernel handles only the E real edges. No cursor array.
__global__ void k_offs2(const int* __restrict__ counts,
                        int* __restrict__ offs, int* __restrict__ srcs, int N) {
    __shared__ int red[4];
    __shared__ int wsum[4];
    int b = blockIdx.x;
    int t = threadIdx.x;
    int lane = t & 63, wid = t >> 6;
    int lim = b << 10;
    int s = 0;
    for (int i = t * 4; i < lim; i += 1024) {
        int4 v = *reinterpret_cast<const int4*>(&counts[i]);
        s += v.x + v.y + v.z + v.w + 4;
    }
    #pragma unroll
    for (int m = 1; m < 64; m <<= 1) s += __shfl_xor(s, m);
    if (lane == 0) red[wid] = s;
    __syncthreads();
    int P = red[0] + red[1] + red[2] + red[3];
    int i0 = (b << 10) + t * 4;
    int c0 = 0, c1 = 0, c2 = 0, c3 = 0;
    if (i0 + 3 < N) {
        int4 cv = *reinterpret_cast<const int4*>(&counts[i0]);
        c0 = cv.x + 1; c1 = cv.y + 1; c2 = cv.z + 1; c3 = cv.w + 1;
    } else {
        if (i0 + 0 < N) c0 = counts[i0 + 0] + 1;
        if (i0 + 1 < N) c1 = counts[i0 + 1] + 1;
        if (i0 + 2 < N) c2 = counts[i0 + 2] + 1;
        if (i0 + 3 < N) c3 = counts[i0 + 3] + 1;
    }
    int tsum = c0 + c1 + c2 + c3;
    int incl = tsum;
    #pragma unroll
    for (int off = 1; off < 64; off <<= 1) {
        int tv = __shfl_up(incl, off);
        if (lane >= off) incl += tv;
    }
    if (lane == 63) wsum[wid] = incl;
    __syncthreads();
    int woff = 0;
    for (int w = 0; w < wid; ++w) woff += wsum[w];
    int base = P + woff + incl - tsum;
    int p0 = base;
    int p1 = p0 + c0;
    int p2 = p1 + c1;
    int p3 = p2 + c2;
    int p4 = p3 + c3;
    if (i0 + 0 < N) { offs[i0 + 1] = p1; srcs[p1 - 1] = i0 + 0; }
    if (i0 + 1 < N) { offs[i0 + 2] = p2; srcs[p2 - 1] = i0 + 1; }
    if (i0 + 2 < N) { offs[i0 + 3] = p3; srcs[p3 - 1] = i0 + 2; }
    if (i0 + 3 < N) { offs[i0 + 4] = p4; srcs[p4 - 1] = i0 + 3; }
    if (b == 0 && t == 0) offs[0] = 0;
}

// K_scatter: E edges only; position precomputed (epos), segment base via
// random-but-L2-hot offs read (200KB table) -- no atomics.
__global__ void k_scatter(const int* __restrict__ ei, const int* __restrict__ offs,
                          const int* __restrict__ epos, int* __restrict__ srcs, int E) {
    int t = blockIdx.x * blockDim.x + threadIdx.x;
    if (t < E) {
        int s = ei[t], d = ei[E + t];
        srcs[offs[d] + epos[t]] = s;
    }
}

// K_agg1n2: agg1 + node2 tail via LDS.
// Main loop FLAT-UNROLL-16: 16 b64 gather loads in flight per wave
// (R13 diagnosis: gather is outstanding-load-limited -- 256 loads/CU at
// ~900cy miss latency sustains only ~2.7 TB/s; 16-deep doubles it).
// __launch_bounds__(256,8) caps VGPR at 64 (the R5/R7 occupancy cliff).
// W2 staging dst-linear (conflict-free, R13); feat_lds linear (residual
// 4-way broadcast read ~3e6 cyc, cheaper than swizzle VALU -- R12).
// LDS 20480 B = exactly 8 blocks/CU (R11).
__global__ void __launch_bounds__(256, 8)
k_agg1n2(const __half* __restrict__ h1h, const float* __restrict__ as1,
         const float* __restrict__ ad1, const float* __restrict__ b1,
         const float* __restrict__ W2, const float* __restrict__ att_s2,
         const float* __restrict__ att_d2,
         const int* __restrict__ offs, const int* __restrict__ srcs,
         __half* __restrict__ h2h, float* __restrict__ as2,
         float* __restrict__ ad2, int N) {
    __shared__ float w_lds[4096];
    __shared__ float feat_lds[1024];
    int t = threadIdx.x;
    #pragma unroll
    for (int p = 0; p < 4; ++p) {
        int dw = p * 1024 + t * 4;
        int hi = dw >> 11;
        int r = dw & 2047;
        int row = r >> 5;
        int rem = r & 31;
        int half = rem >> 4;
        int o = rem & 15;
        int k = (hi << 7) | (half << 6) | row;
        *reinterpret_cast<float4*>(&w_lds[dw]) =
            *reinterpret_cast<const float4*>(&W2[k * 16 + o]);
    }
    __syncthreads();

    int wid = t >> 6;
    int d = blockIdx.x * 4 + wid;
    if (d >= N) return;
    int lane = t & 63;
    int head = lane >> 3;
    int po = lane >> 3;
    int ph = lane & 7;
    float ad_p = ad1[d * 8 + ph];
    int beg = offs[d], end = offs[d + 1];
    float denom = 0.f, a0 = 0.f, a1 = 0.f, a2 = 0.f, a3 = 0.f;
    for (int cb = beg; cb < end; cb += 64) {
        int idx = cb + lane;
        int myS = srcs[idx < end ? idx : end - 1];
        int cnt = min(64, end - cb);   // wave-uniform
        float p8[8];
        #pragma unroll
        for (int j = 0; j < 8; ++j) {
            int s = __shfl(myS, po * 8 + j);
            p8[j] = __expf(leaky02(as1[s * 8 + ph] + ad_p));
        }
        for (int kb = 0; kb < cnt; kb += 16) {
            #pragma unroll
            for (int u = 0; u < 16; ++u) {
                int k = kb + u;            // wave-uniform
                if (k < cnt) {             // uniform branch: convergent shfls
                    int s = __shfl(myS, k);
                    float p = __shfl(p8[u & 7], (k & ~7) + head);
                    denom += p;
                    uint2 raw = *reinterpret_cast<const uint2*>(
                        h1h + (size_t)s * 256 + lane * 4);
                    union { unsigned uu; __half2 h; } u0, u1;
                    u0.uu = raw.x; u1.uu = raw.y;
                    float2 f01 = __half22float2(u0.h);
                    float2 f23 = __half22float2(u1.h);
                    a0 += p * f01.x; a1 += p * f01.y;
                    a2 += p * f23.x; a3 += p * f23.y;
                }
            }
        }
    }
    float inv = 1.f / (denom + 1e-16f);
    int c = lane * 4;
    float4 bv = *reinterpret_cast<const float4*>(&b1[c]);
    float r0 = a0 * inv + bv.x;
    float r1 = a1 * inv + bv.y;
    float r2 = a2 * inv + bv.z;
    float r3 = a3 * inv + bv.w;
    r0 = r0 > 0.f ? r0 : (__expf(r0) - 1.f);
    r1 = r1 > 0.f ? r1 : (__expf(r1) - 1.f);
    r2 = r2 > 0.f ? r2 : (__expf(r2) - 1.f);
    r3 = r3 > 0.f ? r3 : (__expf(r3) - 1.f);
    // ---- node2 tail: feat -> LDS (wave-private row; no barrier needed) ----
    float4 fv; fv.x = r0; fv.y = r1; fv.z = r2; fv.w = r3;
    *reinterpret_cast<float4*>(&feat_lds[wid * 256 + c]) = fv;
    int o = lane & 15, q = lane >> 4;
    const float* fl = &feat_lds[wid * 256 + q * 64];
    const float* w = w_lds + ((q >> 1) << 11) + ((q & 1) << 4) + o;  // + j*32
    float acc = 0.f;
    #pragma unroll 8
    for (int j = 0; j < 64; ++j)
        acc += fl[j] * w[j * 32];
    acc += __shfl_xor(acc, 16);
    acc += __shfl_xor(acc, 32);    // all lanes hold h2[d][o]
    if (lane < 16) h2h[d * 16 + o] = __float2half(acc);
    float ts = acc * att_s2[o], td = acc * att_d2[o];
    #pragma unroll
    for (int m = 1; m < 16; m <<= 1) {
        ts += __shfl_xor(ts, m);
        td += __shfl_xor(td, m);
    }
    if (lane == 0) { as2[d] = ts; ad2[d] = td; }
}

// K_agg2: one wave per dst. 16 edge-groups x 4 lanes owning 4 channels each.
// All lanes execute every shfl (convergent); accumulate predicated only.
__global__ void k_agg2(const __half* __restrict__ h2h, const float* __restrict__ as2,
                       const float* __restrict__ ad2, const float* __restrict__ b2,
                       const int* __restrict__ offs, const int* __restrict__ srcs,
                       float* __restrict__ out, int N) {
    int wid = threadIdx.x >> 6;
    int d = blockIdx.x * 4 + wid;
    if (d >= N) return;
    int lane = threadIdx.x & 63;
    int cl = lane & 3, eg = lane >> 2;
    float ad = ad2[d];
    int beg = offs[d], end = offs[d + 1];
    float denom = 0.f, a0 = 0.f, a1 = 0.f, a2 = 0.f, a3 = 0.f;
    for (int cb = beg; cb < end; cb += 64) {
        int idx = cb + lane;
        int myS = srcs[idx < end ? idx : end - 1];
        #pragma unroll
        for (int cc = 0; cc < 4; ++cc) {
            int s = __shfl(myS, cc * 16 + eg);   // convergent
            int epos2 = cb + cc * 16 + eg;
            if (epos2 < end) {
                float e = leaky02(as2[s] + ad);
                float p = __expf(e);
                denom += p;
                uint2 raw = *reinterpret_cast<const uint2*>(h2h + (size_t)s * 16 + cl * 4);
                union { unsigned u; __half2 h; } u0, u1;
                u0.u = raw.x; u1.u = raw.y;
                float2 f01 = __half22float2(u0.h);
                float2 f23 = __half22float2(u1.h);
                a0 += p * f01.x; a1 += p * f01.y; a2 += p * f23.x; a3 += p * f23.y;
            }
        }
    }
    #pragma unroll
    for (int m = 4; m < 64; m <<= 1) {
        denom += __shfl_xor(denom, m);
        a0 += __shfl_xor(a0, m);
        a1 += __shfl_xor(a1, m);
        a2 += __shfl_xor(a2, m);
        a3 += __shfl_xor(a3, m);
    }
    if (eg == 0) {
        float inv = 1.f / (denom + 1e-16f);
        int c = cl * 4;
        float4 r;
        r.x = a0 * inv + b2[c + 0];
        r.y = a1 * inv + b2[c + 1];
        r.z = a2 * inv + b2[c + 2];
        r.w = a3 * inv + b2[c + 3];
        *reinterpret_cast<float4*>(&out[d * 16 + c]) = r;
    }
}

extern "C" void kernel_launch(void* const* d_in, const int* in_sizes, int n_in,
                              void* d_out, int out_size, void* d_ws, size_t ws_size,
                              hipStream_t stream) {
    const float* x       = (const float*)d_in[0];
    const int*   ei      = (const int*)d_in[1];
    const float* W1      = (const float*)d_in[2];
    const float* att_s1  = (const float*)d_in[3];
    const float* att_d1  = (const float*)d_in[4];
    const float* b1      = (const float*)d_in[5];
    const float* W2      = (const float*)d_in[6];
    const float* att_s2  = (const float*)d_in[7];
    const float* att_d2  = (const float*)d_in[8];
    const float* b2      = (const float*)d_in[9];
    float* out = (float*)d_out;

    const int N = in_sizes[0] / 3;
    const int E = in_sizes[1] / 2;
    const int Etot = E + N;
    const int NB = (N + 1023) / 1024;  // scan blocks

    // carve workspace (16B aligned slices)
    char* w = (char*)d_ws;
    auto alloc = [&](size_t bytes) -> void* {
        void* p = (void*)w;
        w += (bytes + 15) & ~(size_t)15;
        return p;
    };
    int* counts   = (int*)alloc((size_t)N * 4);
    int* offs     = (int*)alloc((size_t)(N + 1) * 4);
    int* epos     = (int*)alloc((size_t)E * 4);
    int* srcs     = (int*)alloc((size_t)Etot * 4);
    __half* h1h   = (__half*)alloc((size_t)N * 256 * 2);
    float* as1    = (float*)alloc((size_t)N * 8 * 4);
    float* ad1    = (float*)alloc((size_t)N * 8 * 4);
    __half* h2h   = (__half*)alloc((size_t)N * 16 * 2);
    float* as2    = (float*)alloc((size_t)N * 4);
    float* ad2    = (float*)alloc((size_t)N * 4);
    (void)ws_size; (void)n_in; (void)out_size;

    const int B = 256;
    const int NB1 = (N + 3) / 4;            // node1 blocks in k_prep
    const int NBc = (E + B - 1) / B;        // count blocks in k_prep

    hipMemsetAsync(counts, 0, (size_t)N * 4, stream);
    hipLaunchKernelGGL(k_prep, dim3(NB1 + NBc), dim3(B), 0, stream,
                       x, W1, att_s1, att_d1, h1h, as1, ad1, ei, counts, epos, N, E, NB1);
    hipLaunchKernelGGL(k_offs2, dim3(NB), dim3(B), 0, stream, counts, offs, srcs, N);
    hipLaunchKernelGGL(k_scatter, dim3((E + B - 1) / B), dim3(B), 0, stream,
                       ei, offs, epos, srcs, E);
    hipLaunchKernelGGL(k_agg1n2, dim3((N + 3) / 4), dim3(B), 0, stream,
                       h1h, as1, ad1, b1, W2, att_s2, att_d2, offs, srcs,
                       h2h, as2, ad2, N);
    hipLaunchKernelGGL(k_agg2, dim3((N + 3) / 4), dim3(B), 0, stream,
                       h2h, as2, ad2, b2, offs, srcs, out, N);
}

// Round 16
// 199.331 us; speedup vs baseline: 1.2479x; 1.1255x over previous
//
#include <hip/hip_runtime.h>
#include <hip/hip_bf16.h>
#include <hip/hip_fp16.h>
#include <math.h>

__device__ __forceinline__ float leaky02(float x) { return x > 0.f ? x : 0.2f * x; }

// K_prep: fat kernel. Blocks [0,NB1): node1 transform. Blocks [NB1,...):
// edge dst count + per-edge position (epos = old count), coalesced store.
__global__ void k_prep(const float* __restrict__ x, const float* __restrict__ W1,
                       const float* __restrict__ att_s, const float* __restrict__ att_d,
                       __half* __restrict__ h1h, float* __restrict__ as1,
                       float* __restrict__ ad1,
                       const int* __restrict__ ei, int* __restrict__ counts,
                       int* __restrict__ epos,
                       int N, int E, int NB1) {
    int b = blockIdx.x;
    if (b < NB1) {
        int wid = threadIdx.x >> 6;
        int n = b * 4 + wid;
        if (n >= N) return;
        int lane = threadIdx.x & 63;
        int c = lane * 4;
        float x0 = x[n * 3 + 0], x1 = x[n * 3 + 1], x2 = x[n * 3 + 2];
        float4 w0 = *reinterpret_cast<const float4*>(&W1[c]);
        float4 w1 = *reinterpret_cast<const float4*>(&W1[256 + c]);
        float4 w2 = *reinterpret_cast<const float4*>(&W1[512 + c]);
        float h0 = x0 * w0.x + x1 * w1.x + x2 * w2.x;
        float h1_ = x0 * w0.y + x1 * w1.y + x2 * w2.y;
        float h2_ = x0 * w0.z + x1 * w1.z + x2 * w2.z;
        float h3 = x0 * w0.w + x1 * w1.w + x2 * w2.w;
        union { __half2 h[2]; uint2 u; } pk;
        pk.h[0] = __floats2half2_rn(h0, h1_);
        pk.h[1] = __floats2half2_rn(h2_, h3);
        *reinterpret_cast<uint2*>(h1h + (size_t)n * 256 + c) = pk.u;
        float4 as = *reinterpret_cast<const float4*>(&att_s[c]);
        float4 ad = *reinterpret_cast<const float4*>(&att_d[c]);
        float vs = h0 * as.x + h1_ * as.y + h2_ * as.z + h3 * as.w;
        float vd = h0 * ad.x + h1_ * ad.y + h2_ * ad.z + h3 * ad.w;
        #pragma unroll
        for (int m = 1; m < 8; m <<= 1) {
            vs += __shfl_xor(vs, m);
            vd += __shfl_xor(vd, m);
        }
        if ((lane & 7) == 0) {
            as1[n * 8 + (lane >> 3)] = vs;
            ad1[n * 8 + (lane >> 3)] = vd;
        }
    } else {
        int t = (b - NB1) * blockDim.x + threadIdx.x;
        if (t < E) {
            int d = ei[E + t];
            epos[t] = atomicAdd(&counts[d], 1);   // position within dst segment
        }
    }
}

// K_offs2: per-block offsets; block computes its own prefix. Also places the
// self-loop at the LAST slot of each segment (srcs[offs[i+1]-1] = i).
__global__ void k_offs2(const int* __restrict__ counts,
                        int* __restrict__ offs, int* __restrict__ srcs, int N) {
    __shared__ int red[4];
    __shared__ int wsum[4];
    int b = blockIdx.x;
    int t = threadIdx.x;
    int lane = t & 63, wid = t >> 6;
    int lim = b << 10;
    int s = 0;
    for (int i = t * 4; i < lim; i += 1024) {
        int4 v = *reinterpret_cast<const int4*>(&counts[i]);
        s += v.x + v.y + v.z + v.w + 4;
    }
    #pragma unroll
    for (int m = 1; m < 64; m <<= 1) s += __shfl_xor(s, m);
    if (lane == 0) red[wid] = s;
    __syncthreads();
    int P = red[0] + red[1] + red[2] + red[3];
    int i0 = (b << 10) + t * 4;
    int c0 = 0, c1 = 0, c2 = 0, c3 = 0;
    if (i0 + 3 < N) {
        int4 cv = *reinterpret_cast<const int4*>(&counts[i0]);
        c0 = cv.x + 1; c1 = cv.y + 1; c2 = cv.z + 1; c3 = cv.w + 1;
    } else {
        if (i0 + 0 < N) c0 = counts[i0 + 0] + 1;
        if (i0 + 1 < N) c1 = counts[i0 + 1] + 1;
        if (i0 + 2 < N) c2 = counts[i0 + 2] + 1;
        if (i0 + 3 < N) c3 = counts[i0 + 3] + 1;
    }
    int tsum = c0 + c1 + c2 + c3;
    int incl = tsum;
    #pragma unroll
    for (int off = 1; off < 64; off <<= 1) {
        int tv = __shfl_up(incl, off);
        if (lane >= off) incl += tv;
    }
    if (lane == 63) wsum[wid] = incl;
    __syncthreads();
    int woff = 0;
    for (int w = 0; w < wid; ++w) woff += wsum[w];
    int base = P + woff + incl - tsum;
    int p0 = base;
    int p1 = p0 + c0;
    int p2 = p1 + c1;
    int p3 = p2 + c2;
    int p4 = p3 + c3;
    if (i0 + 0 < N) { offs[i0 + 1] = p1; srcs[p1 - 1] = i0 + 0; }
    if (i0 + 1 < N) { offs[i0 + 2] = p2; srcs[p2 - 1] = i0 + 1; }
    if (i0 + 2 < N) { offs[i0 + 3] = p3; srcs[p3 - 1] = i0 + 2; }
    if (i0 + 3 < N) { offs[i0 + 4] = p4; srcs[p4 - 1] = i0 + 3; }
    if (b == 0 && t == 0) offs[0] = 0;
}

// K_scatter: E edges only; position precomputed (epos); no atomics.
__global__ void k_scatter(const int* __restrict__ ei, const int* __restrict__ offs,
                          const int* __restrict__ epos, int* __restrict__ srcs, int E) {
    int t = blockIdx.x * blockDim.x + threadIdx.x;
    if (t < E) {
        int s = ei[t], d = ei[E + t];
        srcs[offs[d] + epos[t]] = s;
    }
}

// K_agg1n2: agg1 + node2 tail via LDS.
// Inner loop BRANCH-FREE + EXPLICITLY BATCHED: all 8 (s,p) computed first
// (p = 0 for the k>=cnt tail -- numerically exact), then 8 unconditional
// uint2 loads into raw[8] (clamped myS keeps addresses valid), then the
// accumulate. The live raw[8] FORCES 8 loads in flight (R14: the branched
// form pinned VGPR at 28 = ~4 loads in flight; gather is MLP-limited).
// All shfls unconditional -> convergent; arrays statically indexed (rule 20).
// W2 staging dst-linear (conflict-free, R13); feat_lds linear (R12);
// LDS 20480 B = exactly 8 blocks/CU (R11); VGPR capped 64 (R5/R7 cliff).
__global__ void __launch_bounds__(256, 8)
k_agg1n2(const __half* __restrict__ h1h, const float* __restrict__ as1,
         const float* __restrict__ ad1, const float* __restrict__ b1,
         const float* __restrict__ W2, const float* __restrict__ att_s2,
         const float* __restrict__ att_d2,
         const int* __restrict__ offs, const int* __restrict__ srcs,
         __half* __restrict__ h2h, float* __restrict__ as2,
         float* __restrict__ ad2, int N) {
    __shared__ float w_lds[4096];
    __shared__ float feat_lds[1024];
    int t = threadIdx.x;
    #pragma unroll
    for (int p = 0; p < 4; ++p) {
        int dw = p * 1024 + t * 4;
        int hi = dw >> 11;
        int r = dw & 2047;
        int row = r >> 5;
        int rem = r & 31;
        int half = rem >> 4;
        int o = rem & 15;
        int k = (hi << 7) | (half << 6) | row;
        *reinterpret_cast<float4*>(&w_lds[dw]) =
            *reinterpret_cast<const float4*>(&W2[k * 16 + o]);
    }
    __syncthreads();

    int wid = t >> 6;
    int d = blockIdx.x * 4 + wid;
    if (d >= N) return;
    int lane = t & 63;
    int head = lane >> 3;
    int po = lane >> 3;
    int ph = lane & 7;
    float ad_p = ad1[d * 8 + ph];
    int beg = offs[d], end = offs[d + 1];
    float denom = 0.f, a0 = 0.f, a1 = 0.f, a2 = 0.f, a3 = 0.f;
    for (int cb = beg; cb < end; cb += 64) {
        int idx = cb + lane;
        int myS = srcs[idx < end ? idx : end - 1];
        int cnt = min(64, end - cb);   // wave-uniform
        float p8[8];
        #pragma unroll
        for (int j = 0; j < 8; ++j) {
            int s = __shfl(myS, po * 8 + j);
            p8[j] = __expf(leaky02(as1[s * 8 + ph] + ad_p));
        }
        for (int kb = 0; kb < cnt; kb += 8) {
            int sA[8];
            float pA[8];
            #pragma unroll
            for (int j = 0; j < 8; ++j) {
                int k = kb + j;                      // wave-uniform
                sA[j] = __shfl(myS, k);              // convergent (clamped)
                float pv = __shfl(p8[j], kb + head); // convergent
                pA[j] = (k < cnt) ? pv : 0.f;        // exact: +0 adds nothing
            }
            uint2 raw[8];
            #pragma unroll
            for (int j = 0; j < 8; ++j)
                raw[j] = *reinterpret_cast<const uint2*>(
                    h1h + (size_t)sA[j] * 256 + lane * 4);
            #pragma unroll
            for (int j = 0; j < 8; ++j) {
                union { unsigned uu; __half2 h; } u0, u1;
                u0.uu = raw[j].x; u1.uu = raw[j].y;
                float2 f01 = __half22float2(u0.h);
                float2 f23 = __half22float2(u1.h);
                denom += pA[j];
                a0 += pA[j] * f01.x; a1 += pA[j] * f01.y;
                a2 += pA[j] * f23.x; a3 += pA[j] * f23.y;
            }
        }
    }
    float inv = 1.f / (denom + 1e-16f);
    int c = lane * 4;
    float4 bv = *reinterpret_cast<const float4*>(&b1[c]);
    float r0 = a0 * inv + bv.x;
    float r1 = a1 * inv + bv.y;
    float r2 = a2 * inv + bv.z;
    float r3 = a3 * inv + bv.w;
    r0 = r0 > 0.f ? r0 : (__expf(r0) - 1.f);
    r1 = r1 > 0.f ? r1 : (__expf(r1) - 1.f);
    r2 = r2 > 0.f ? r2 : (__expf(r2) - 1.f);
    r3 = r3 > 0.f ? r3 : (__expf(r3) - 1.f);
    // ---- node2 tail: feat -> LDS (wave-private row; no barrier needed) ----
    float4 fv; fv.x = r0; fv.y = r1; fv.z = r2; fv.w = r3;
    *reinterpret_cast<float4*>(&feat_lds[wid * 256 + c]) = fv;
    int o = lane & 15, q = lane >> 4;
    const float* fl = &feat_lds[wid * 256 + q * 64];
    const float* w = w_lds + ((q >> 1) << 11) + ((q & 1) << 4) + o;  // + j*32
    float acc = 0.f;
    #pragma unroll 8
    for (int j = 0; j < 64; ++j)
        acc += fl[j] * w[j * 32];
    acc += __shfl_xor(acc, 16);
    acc += __shfl_xor(acc, 32);    // all lanes hold h2[d][o]
    if (lane < 16) h2h[d * 16 + o] = __float2half(acc);
    float ts = acc * att_s2[o], td = acc * att_d2[o];
    #pragma unroll
    for (int m = 1; m < 16; m <<= 1) {
        ts += __shfl_xor(ts, m);
        td += __shfl_xor(td, m);
    }
    if (lane == 0) { as2[d] = ts; ad2[d] = td; }
}

// K_agg2: one wave per dst. 16 edge-groups x 4 lanes owning 4 channels each.
// All lanes execute every shfl (convergent); accumulate predicated only.
__global__ void k_agg2(const __half* __restrict__ h2h, const float* __restrict__ as2,
                       const float* __restrict__ ad2, const float* __restrict__ b2,
                       const int* __restrict__ offs, const int* __restrict__ srcs,
                       float* __restrict__ out, int N) {
    int wid = threadIdx.x >> 6;
    int d = blockIdx.x * 4 + wid;
    if (d >= N) return;
    int lane = threadIdx.x & 63;
    int cl = lane & 3, eg = lane >> 2;
    float ad = ad2[d];
    int beg = offs[d], end = offs[d + 1];
    float denom = 0.f, a0 = 0.f, a1 = 0.f, a2 = 0.f, a3 = 0.f;
    for (int cb = beg; cb < end; cb += 64) {
        int idx = cb + lane;
        int myS = srcs[idx < end ? idx : end - 1];
        #pragma unroll
        for (int cc = 0; cc < 4; ++cc) {
            int s = __shfl(myS, cc * 16 + eg);   // convergent
            int epos2 = cb + cc * 16 + eg;
            if (epos2 < end) {
                float e = leaky02(as2[s] + ad);
                float p = __expf(e);
                denom += p;
                uint2 raw = *reinterpret_cast<const uint2*>(h2h + (size_t)s * 16 + cl * 4);
                union { unsigned u; __half2 h; } u0, u1;
                u0.u = raw.x; u1.u = raw.y;
                float2 f01 = __half22float2(u0.h);
                float2 f23 = __half22float2(u1.h);
                a0 += p * f01.x; a1 += p * f01.y; a2 += p * f23.x; a3 += p * f23.y;
            }
        }
    }
    #pragma unroll
    for (int m = 4; m < 64; m <<= 1) {
        denom += __shfl_xor(denom, m);
        a0 += __shfl_xor(a0, m);
        a1 += __shfl_xor(a1, m);
        a2 += __shfl_xor(a2, m);
        a3 += __shfl_xor(a3, m);
    }
    if (eg == 0) {
        float inv = 1.f / (denom + 1e-16f);
        int c = cl * 4;
        float4 r;
        r.x = a0 * inv + b2[c + 0];
        r.y = a1 * inv + b2[c + 1];
        r.z = a2 * inv + b2[c + 2];
        r.w = a3 * inv + b2[c + 3];
        *reinterpret_cast<float4*>(&out[d * 16 + c]) = r;
    }
}

extern "C" void kernel_launch(void* const* d_in, const int* in_sizes, int n_in,
                              void* d_out, int out_size, void* d_ws, size_t ws_size,
                              hipStream_t stream) {
    const float* x       = (const float*)d_in[0];
    const int*   ei      = (const int*)d_in[1];
    const float* W1      = (const float*)d_in[2];
    const float* att_s1  = (const float*)d_in[3];
    const float* att_d1  = (const float*)d_in[4];
    const float* b1      = (const float*)d_in[5];
    const float* W2      = (const float*)d_in[6];
    const float* att_s2  = (const float*)d_in[7];
    const float* att_d2  = (const float*)d_in[8];
    const float* b2      = (const float*)d_in[9];
    float* out = (float*)d_out;

    const int N = in_sizes[0] / 3;
    const int E = in_sizes[1] / 2;
    const int Etot = E + N;
    const int NB = (N + 1023) / 1024;  // scan blocks

    // carve workspace (16B aligned slices)
    char* w = (char*)d_ws;
    auto alloc = [&](size_t bytes) -> void* {
        void* p = (void*)w;
        w += (bytes + 15) & ~(size_t)15;
        return p;
    };
    int* counts   = (int*)alloc((size_t)N * 4);
    int* offs     = (int*)alloc((size_t)(N + 1) * 4);
    int* epos     = (int*)alloc((size_t)E * 4);
    int* srcs     = (int*)alloc((size_t)Etot * 4);
    __half* h1h   = (__half*)alloc((size_t)N * 256 * 2);
    float* as1    = (float*)alloc((size_t)N * 8 * 4);
    float* ad1    = (float*)alloc((size_t)N * 8 * 4);
    __half* h2h   = (__half*)alloc((size_t)N * 16 * 2);
    float* as2    = (float*)alloc((size_t)N * 4);
    float* ad2    = (float*)alloc((size_t)N * 4);
    (void)ws_size; (void)n_in; (void)out_size;

    const int B = 256;
    const int NB1 = (N + 3) / 4;            // node1 blocks in k_prep
    const int NBc = (E + B - 1) / B;        // count blocks in k_prep

    hipMemsetAsync(counts, 0, (size_t)N * 4, stream);
    hipLaunchKernelGGL(k_prep, dim3(NB1 + NBc), dim3(B), 0, stream,
                       x, W1, att_s1, att_d1, h1h, as1, ad1, ei, counts, epos, N, E, NB1);
    hipLaunchKernelGGL(k_offs2, dim3(NB), dim3(B), 0, stream, counts, offs, srcs, N);
    hipLaunchKernelGGL(k_scatter, dim3((E + B - 1) / B), dim3(B), 0, stream,
                       ei, offs, epos, srcs, E);
    hipLaunchKernelGGL(k_agg1n2, dim3((N + 3) / 4), dim3(B), 0, stream,
                       h1h, as1, ad1, b1, W2, att_s2, att_d2, offs, srcs,
                       h2h, as2, ad2, N);
    hipLaunchKernelGGL(k_agg2, dim3((N + 3) / 4), dim3(B), 0, stream,
                       h2h, as2, ad2, b2, offs, srcs, out, N);
}

// Round 17
// 177.771 us; speedup vs baseline: 1.3992x; 1.1213x over previous
//
#include <hip/hip_runtime.h>
#include <hip/hip_bf16.h>
#include <hip/hip_fp16.h>
#include <math.h>

__device__ __forceinline__ float leaky02(float x) { return x > 0.f ? x : 0.2f * x; }

#define CPAD 32   // counters padded to one 128B line each (R16 atomic theory)

// K_prep: fat kernel. Blocks [0,NBc): edge dst count+rank (returning atomic
// on LINE-PADDED counters -- R16: 800K atomics on a packed 200KB table ran
// at ~4/cy, suspected same-line serialization; padding gives each counter
// its own 128B line). Count blocks FIRST so atomics overlap node1 work.
// Blocks [NBc,...): node1 transform (one wave per node).
__global__ void k_prep(const float* __restrict__ x, const float* __restrict__ W1,
                       const float* __restrict__ att_s, const float* __restrict__ att_d,
                       __half* __restrict__ h1h, float* __restrict__ as1,
                       float* __restrict__ ad1,
                       const int* __restrict__ ei, int* __restrict__ counts_pad,
                       int* __restrict__ epos,
                       int N, int E, int NBc) {
    int b = blockIdx.x;
    if (b < NBc) {
        int t = b * blockDim.x + threadIdx.x;
        if (t < E) {
            int d = ei[E + t];
            epos[t] = atomicAdd(&counts_pad[(size_t)d * CPAD], 1);
        }
        return;
    }
    int nb = b - NBc;
    int wid = threadIdx.x >> 6;
    int n = nb * 4 + wid;
    if (n >= N) return;
    int lane = threadIdx.x & 63;
    int c = lane * 4;
    float x0 = x[n * 3 + 0], x1 = x[n * 3 + 1], x2 = x[n * 3 + 2];
    float4 w0 = *reinterpret_cast<const float4*>(&W1[c]);
    float4 w1 = *reinterpret_cast<const float4*>(&W1[256 + c]);
    float4 w2 = *reinterpret_cast<const float4*>(&W1[512 + c]);
    float h0 = x0 * w0.x + x1 * w1.x + x2 * w2.x;
    float h1_ = x0 * w0.y + x1 * w1.y + x2 * w2.y;
    float h2_ = x0 * w0.z + x1 * w1.z + x2 * w2.z;
    float h3 = x0 * w0.w + x1 * w1.w + x2 * w2.w;
    union { __half2 h[2]; uint2 u; } pk;
    pk.h[0] = __floats2half2_rn(h0, h1_);
    pk.h[1] = __floats2half2_rn(h2_, h3);
    *reinterpret_cast<uint2*>(h1h + (size_t)n * 256 + c) = pk.u;
    float4 as = *reinterpret_cast<const float4*>(&att_s[c]);
    float4 ad = *reinterpret_cast<const float4*>(&att_d[c]);
    float vs = h0 * as.x + h1_ * as.y + h2_ * as.z + h3 * as.w;
    float vd = h0 * ad.x + h1_ * ad.y + h2_ * ad.z + h3 * ad.w;
    #pragma unroll
    for (int m = 1; m < 8; m <<= 1) {
        vs += __shfl_xor(vs, m);
        vd += __shfl_xor(vd, m);
    }
    if ((lane & 7) == 0) {
        as1[n * 8 + (lane >> 3)] = vs;
        ad1[n * 8 + (lane >> 3)] = vd;
    }
}

// K_compact: densify padded counters (one thread per node).
__global__ void k_compact(const int* __restrict__ counts_pad,
                          int* __restrict__ counts, int N) {
    int i = blockIdx.x * blockDim.x + threadIdx.x;
    if (i < N) counts[i] = counts_pad[(size_t)i * CPAD];
}

// K_offs2: per-block offsets; block computes its own prefix (dense counts).
// Also places the self-loop at the LAST slot of each segment.
__global__ void k_offs2(const int* __restrict__ counts,
                        int* __restrict__ offs, int* __restrict__ srcs, int N) {
    __shared__ int red[4];
    __shared__ int wsum[4];
    int b = blockIdx.x;
    int t = threadIdx.x;
    int lane = t & 63, wid = t >> 6;
    int lim = b << 10;
    int s = 0;
    for (int i = t * 4; i < lim; i += 1024) {
        int4 v = *reinterpret_cast<const int4*>(&counts[i]);
        s += v.x + v.y + v.z + v.w + 4;
    }
    #pragma unroll
    for (int m = 1; m < 64; m <<= 1) s += __shfl_xor(s, m);
    if (lane == 0) red[wid] = s;
    __syncthreads();
    int P = red[0] + red[1] + red[2] + red[3];
    int i0 = (b << 10) + t * 4;
    int c0 = 0, c1 = 0, c2 = 0, c3 = 0;
    if (i0 + 3 < N) {
        int4 cv = *reinterpret_cast<const int4*>(&counts[i0]);
        c0 = cv.x + 1; c1 = cv.y + 1; c2 = cv.z + 1; c3 = cv.w + 1;
    } else {
        if (i0 + 0 < N) c0 = counts[i0 + 0] + 1;
        if (i0 + 1 < N) c1 = counts[i0 + 1] + 1;
        if (i0 + 2 < N) c2 = counts[i0 + 2] + 1;
        if (i0 + 3 < N) c3 = counts[i0 + 3] + 1;
    }
    int tsum = c0 + c1 + c2 + c3;
    int incl = tsum;
    #pragma unroll
    for (int off = 1; off < 64; off <<= 1) {
        int tv = __shfl_up(incl, off);
        if (lane >= off) incl += tv;
    }
    if (lane == 63) wsum[wid] = incl;
    __syncthreads();
    int woff = 0;
    for (int w = 0; w < wid; ++w) woff += wsum[w];
    int base = P + woff + incl - tsum;
    int p0 = base;
    int p1 = p0 + c0;
    int p2 = p1 + c1;
    int p3 = p2 + c2;
    int p4 = p3 + c3;
    if (i0 + 0 < N) { offs[i0 + 1] = p1; srcs[p1 - 1] = i0 + 0; }
    if (i0 + 1 < N) { offs[i0 + 2] = p2; srcs[p2 - 1] = i0 + 1; }
    if (i0 + 2 < N) { offs[i0 + 3] = p3; srcs[p3 - 1] = i0 + 2; }
    if (i0 + 3 < N) { offs[i0 + 4] = p4; srcs[p4 - 1] = i0 + 3; }
    if (b == 0 && t == 0) offs[0] = 0;
}

// K_scatter: E edges only; position precomputed (epos); no atomics.
__global__ void k_scatter(const int* __restrict__ ei, const int* __restrict__ offs,
                          const int* __restrict__ epos, int* __restrict__ srcs, int E) {
    int t = blockIdx.x * blockDim.x + threadIdx.x;
    if (t < E) {
        int s = ei[t], d = ei[E + t];
        srcs[offs[d] + epos[t]] = s;
    }
}

// K_agg1n2: agg1 + node2 tail via LDS. (R15 batched-MLP version: 8
// unconditional uint2 loads in flight; p=0 tail; convergent shfls.)
__global__ void __launch_bounds__(256, 8)
k_agg1n2(const __half* __restrict__ h1h, const float* __restrict__ as1,
         const float* __restrict__ ad1, const float* __restrict__ b1,
         const float* __restrict__ W2, const float* __restrict__ att_s2,
         const float* __restrict__ att_d2,
         const int* __restrict__ offs, const int* __restrict__ srcs,
         __half* __restrict__ h2h, float* __restrict__ as2,
         float* __restrict__ ad2, int N) {
    __shared__ float w_lds[4096];
    __shared__ float feat_lds[1024];
    int t = threadIdx.x;
    #pragma unroll
    for (int p = 0; p < 4; ++p) {
        int dw = p * 1024 + t * 4;
        int hi = dw >> 11;
        int r = dw & 2047;
        int row = r >> 5;
        int rem = r & 31;
        int half = rem >> 4;
        int o = rem & 15;
        int k = (hi << 7) | (half << 6) | row;
        *reinterpret_cast<float4*>(&w_lds[dw]) =
            *reinterpret_cast<const float4*>(&W2[k * 16 + o]);
    }
    __syncthreads();

    int wid = t >> 6;
    int d = blockIdx.x * 4 + wid;
    if (d >= N) return;
    int lane = t & 63;
    int head = lane >> 3;
    int po = lane >> 3;
    int ph = lane & 7;
    float ad_p = ad1[d * 8 + ph];
    int beg = offs[d], end = offs[d + 1];
    float denom = 0.f, a0 = 0.f, a1 = 0.f, a2 = 0.f, a3 = 0.f;
    for (int cb = beg; cb < end; cb += 64) {
        int idx = cb + lane;
        int myS = srcs[idx < end ? idx : end - 1];
        int cnt = min(64, end - cb);   // wave-uniform
        float p8[8];
        #pragma unroll
        for (int j = 0; j < 8; ++j) {
            int s = __shfl(myS, po * 8 + j);
            p8[j] = __expf(leaky02(as1[s * 8 + ph] + ad_p));
        }
        for (int kb = 0; kb < cnt; kb += 8) {
            int sA[8];
            float pA[8];
            #pragma unroll
            for (int j = 0; j < 8; ++j) {
                int k = kb + j;                      // wave-uniform
                sA[j] = __shfl(myS, k);              // convergent (clamped)
                float pv = __shfl(p8[j], kb + head); // convergent
                pA[j] = (k < cnt) ? pv : 0.f;        // exact: +0 adds nothing
            }
            uint2 raw[8];
            #pragma unroll
            for (int j = 0; j < 8; ++j)
                raw[j] = *reinterpret_cast<const uint2*>(
                    h1h + (size_t)sA[j] * 256 + lane * 4);
            #pragma unroll
            for (int j = 0; j < 8; ++j) {
                union { unsigned uu; __half2 h; } u0, u1;
                u0.uu = raw[j].x; u1.uu = raw[j].y;
                float2 f01 = __half22float2(u0.h);
                float2 f23 = __half22float2(u1.h);
                denom += pA[j];
                a0 += pA[j] * f01.x; a1 += pA[j] * f01.y;
                a2 += pA[j] * f23.x; a3 += pA[j] * f23.y;
            }
        }
    }
    float inv = 1.f / (denom + 1e-16f);
    int c = lane * 4;
    float4 bv = *reinterpret_cast<const float4*>(&b1[c]);
    float r0 = a0 * inv + bv.x;
    float r1 = a1 * inv + bv.y;
    float r2 = a2 * inv + bv.z;
    float r3 = a3 * inv + bv.w;
    r0 = r0 > 0.f ? r0 : (__expf(r0) - 1.f);
    r1 = r1 > 0.f ? r1 : (__expf(r1) - 1.f);
    r2 = r2 > 0.f ? r2 : (__expf(r2) - 1.f);
    r3 = r3 > 0.f ? r3 : (__expf(r3) - 1.f);
    // ---- node2 tail: feat -> LDS (wave-private row; no barrier needed) ----
    float4 fv; fv.x = r0; fv.y = r1; fv.z = r2; fv.w = r3;
    *reinterpret_cast<float4*>(&feat_lds[wid * 256 + c]) = fv;
    int o = lane & 15, q = lane >> 4;
    const float* fl = &feat_lds[wid * 256 + q * 64];
    const float* w = w_lds + ((q >> 1) << 11) + ((q & 1) << 4) + o;  // + j*32
    float acc = 0.f;
    #pragma unroll 8
    for (int j = 0; j < 64; ++j)
        acc += fl[j] * w[j * 32];
    acc += __shfl_xor(acc, 16);
    acc += __shfl_xor(acc, 32);    // all lanes hold h2[d][o]
    if (lane < 16) h2h[d * 16 + o] = __float2half(acc);
    float ts = acc * att_s2[o], td = acc * att_d2[o];
    #pragma unroll
    for (int m = 1; m < 16; m <<= 1) {
        ts += __shfl_xor(ts, m);
        td += __shfl_xor(td, m);
    }
    if (lane == 0) { as2[d] = ts; ad2[d] = td; }
}

// K_agg2: one wave per dst. 16 edge-groups x 4 lanes owning 4 channels each.
__global__ void k_agg2(const __half* __restrict__ h2h, const float* __restrict__ as2,
                       const float* __restrict__ ad2, const float* __restrict__ b2,
                       const int* __restrict__ offs, const int* __restrict__ srcs,
                       float* __restrict__ out, int N) {
    int wid = threadIdx.x >> 6;
    int d = blockIdx.x * 4 + wid;
    if (d >= N) return;
    int lane = threadIdx.x & 63;
    int cl = lane & 3, eg = lane >> 2;
    float ad = ad2[d];
    int beg = offs[d], end = offs[d + 1];
    float denom = 0.f, a0 = 0.f, a1 = 0.f, a2 = 0.f, a3 = 0.f;
    for (int cb = beg; cb < end; cb += 64) {
        int idx = cb + lane;
        int myS = srcs[idx < end ? idx : end - 1];
        #pragma unroll
        for (int cc = 0; cc < 4; ++cc) {
            int s = __shfl(myS, cc * 16 + eg);   // convergent
            int epos2 = cb + cc * 16 + eg;
            if (epos2 < end) {
                float e = leaky02(as2[s] + ad);
                float p = __expf(e);
                denom += p;
                uint2 raw = *reinterpret_cast<const uint2*>(h2h + (size_t)s * 16 + cl * 4);
                union { unsigned u; __half2 h; } u0, u1;
                u0.u = raw.x; u1.u = raw.y;
                float2 f01 = __half22float2(u0.h);
                float2 f23 = __half22float2(u1.h);
                a0 += p * f01.x; a1 += p * f01.y; a2 += p * f23.x; a3 += p * f23.y;
            }
        }
    }
    #pragma unroll
    for (int m = 4; m < 64; m <<= 1) {
        denom += __shfl_xor(denom, m);
        a0 += __shfl_xor(a0, m);
        a1 += __shfl_xor(a1, m);
        a2 += __shfl_xor(a2, m);
        a3 += __shfl_xor(a3, m);
    }
    if (eg == 0) {
        float inv = 1.f / (denom + 1e-16f);
        int c = cl * 4;
        float4 r;
        r.x = a0 * inv + b2[c + 0];
        r.y = a1 * inv + b2[c + 1];
        r.z = a2 * inv + b2[c + 2];
        r.w = a3 * inv + b2[c + 3];
        *reinterpret_cast<float4*>(&out[d * 16 + c]) = r;
    }
}

extern "C" void kernel_launch(void* const* d_in, const int* in_sizes, int n_in,
                              void* d_out, int out_size, void* d_ws, size_t ws_size,
                              hipStream_t stream) {
    const float* x       = (const float*)d_in[0];
    const int*   ei      = (const int*)d_in[1];
    const float* W1      = (const float*)d_in[2];
    const float* att_s1  = (const float*)d_in[3];
    const float* att_d1  = (const float*)d_in[4];
    const float* b1      = (const float*)d_in[5];
    const float* W2      = (const float*)d_in[6];
    const float* att_s2  = (const float*)d_in[7];
    const float* att_d2  = (const float*)d_in[8];
    const float* b2      = (const float*)d_in[9];
    float* out = (float*)d_out;

    const int N = in_sizes[0] / 3;
    const int E = in_sizes[1] / 2;
    const int Etot = E + N;
    const int NB = (N + 1023) / 1024;  // scan blocks

    // carve workspace (16B aligned slices)
    char* w = (char*)d_ws;
    auto alloc = [&](size_t bytes) -> void* {
        void* p = (void*)w;
        w += (bytes + 15) & ~(size_t)15;
        return p;
    };
    int* counts_pad = (int*)alloc((size_t)N * CPAD * 4);   // 6.4 MB padded
    int* counts     = (int*)alloc((size_t)N * 4);
    int* offs       = (int*)alloc((size_t)(N + 1) * 4);
    int* epos       = (int*)alloc((size_t)E * 4);
    int* srcs       = (int*)alloc((size_t)Etot * 4);
    __half* h1h     = (__half*)alloc((size_t)N * 256 * 2);
    float* as1      = (float*)alloc((size_t)N * 8 * 4);
    float* ad1      = (float*)alloc((size_t)N * 8 * 4);
    __half* h2h     = (__half*)alloc((size_t)N * 16 * 2);
    float* as2      = (float*)alloc((size_t)N * 4);
    float* ad2      = (float*)alloc((size_t)N * 4);
    (void)ws_size; (void)n_in; (void)out_size;

    const int B = 256;
    const int NBc = (E + B - 1) / B;        // count blocks (FIRST in k_prep)
    const int NB1 = (N + 3) / 4;            // node1 blocks

    hipMemsetAsync(counts_pad, 0, (size_t)N * CPAD * 4, stream);
    hipLaunchKernelGGL(k_prep, dim3(NBc + NB1), dim3(B), 0, stream,
                       x, W1, att_s1, att_d1, h1h, as1, ad1, ei, counts_pad, epos,
                       N, E, NBc);
    hipLaunchKernelGGL(k_compact, dim3((N + B - 1) / B), dim3(B), 0, stream,
                       counts_pad, counts, N);
    hipLaunchKernelGGL(k_offs2, dim3(NB), dim3(B), 0, stream, counts, offs, srcs, N);
    hipLaunchKernelGGL(k_scatter, dim3((E + B - 1) / B), dim3(B), 0, stream,
                       ei, offs, epos, srcs, E);
    hipLaunchKernelGGL(k_agg1n2, dim3((N + 3) / 4), dim3(B), 0, stream,
                       h1h, as1, ad1, b1, W2, att_s2, att_d2, offs, srcs,
                       h2h, as2, ad2, N);
    hipLaunchKernelGGL(k_agg2, dim3((N + 3) / 4), dim3(B), 0, stream,
                       h2h, as2, ad2, b2, offs, srcs, out, N);
}